// Round 18
// baseline (348.525 us; speedup 1.0000x reference)
//
#include <hip/hip_runtime.h>
#include <hip/hip_bf16.h>

typedef float f4  __attribute__((ext_vector_type(4)));
typedef short s8v __attribute__((ext_vector_type(8)));
typedef short s4v __attribute__((ext_vector_type(4)));

#define MFMA16(a, b, c) __builtin_amdgcn_mfma_f32_16x16x32_bf16((a), (b), (c), 0, 0, 0)

// Packed RNE f32->bf16 pair via compiler intrinsic (emits v_cvt_pk_bf16_f32).
__device__ __forceinline__ unsigned cvtpk(float a, float b) {
  __hip_bfloat162 h2 = __float22bfloat162_rn(make_float2(a, b));
  unsigned u;
  __builtin_memcpy(&u, &h2, 4);
  return u;
}
__device__ __forceinline__ float bf2f(unsigned short s) {
  union { unsigned u; float f; } x; x.u = ((unsigned)s) << 16; return x.f;
}
__device__ __forceinline__ s8v cvt8(const float* p) {
  float4 a = *(const float4*)p;
  float4 b = *(const float4*)(p + 4);
  union { unsigned u[4]; s8v v; } r;
  r.u[0] = cvtpk(a.x, a.y); r.u[1] = cvtpk(a.z, a.w);
  r.u[2] = cvtpk(b.x, b.y); r.u[3] = cvtpk(b.z, b.w);
  return r.v;
}
__device__ __forceinline__ s8v mk8(unsigned a0, unsigned a1, unsigned b0, unsigned b1) {
  union { unsigned u[4]; s8v v; } r;
  r.u[0] = a0; r.u[1] = a1; r.u[2] = b0; r.u[3] = b1;
  return r.v;
}
// Two b64 LDS reads -> one 8-bf16 A-operand (slots j0..3 from p0, j4..7 from p1).
__device__ __forceinline__ s8v ld44(const short* p0, const short* p1) {
  s4v a = *(const s4v*)p0;
  s4v b = *(const s4v*)p1;
  s8v r;
  r[0] = a[0]; r[1] = a[1]; r[2] = a[2]; r[3] = a[3];
  r[4] = b[0]; r[5] = b[1]; r[6] = b[2]; r[7] = b[3];
  return r;
}

// Batch-pipelined: 1024 blocks x 4 batches. All blocks co-resident
// (4 blk/CU x 32KiB LDS = 128KiB, VGPR<=64 -> 16 waves/CU steady, no tail).
// Next batch's X loads issue at top of phase 2 into the dead xf regs ->
// ~900cy HBM latency hides under ~2000cy of phase-2 compute (R17 analysis:
// waves idle ~70% on serial chains; X-load is the head of the chain).
#define NBLK 1024
#define NIT  4

__global__ __launch_bounds__(256, 4)
void attn_head(const void* __restrict__ xg, const void* __restrict__ wqg,
               const void* __restrict__ wkg, const void* __restrict__ wvg,
               void* __restrict__ outg) {
  // Ks: K[s][h] at s*64 + (h ^ ((s&15)<<2))   (XOR swizzle, 8B granules)
  // Vt: V^T[h][s] at h*128 + (s ^ ((h&15)<<2))
  // All 8B accesses conflict-free (R5/R6/R15/R17 measured 0 conflicts).
  __shared__ __align__(16) short smem[16384];
  short* Ksm = smem;           // 128*64 shorts
  short* Vt  = smem + 8192;    // 64*128 shorts

  const int tid  = threadIdx.x;
  const int wave = tid >> 6;
  const int lane = tid & 63;
  const int c16  = lane & 15;
  const int quad = lane >> 4;
  const int b0   = blockIdx.x;
  const int swz  = c16 << 2;

  // ---- barrier-free dtype detect: every wave samples the SAME 64 shorts ----
  int isbf;
  {
    const unsigned short* w = (const unsigned short*)wqg;
    float f = bf2f(w[lane]);
    float a = fabsf(f);
    int ok = (f == 0.0f || (a >= 1e-4f && a <= 1e4f)) ? 1 : 0;
    unsigned long long ball = __ballot(ok);
    isbf = (__popcll(ball) >= 58) ? 1 : 0;
  }

  const int mts[2] = {wave, 7 - wave};   // balanced causal split
  // batch-invariant per-lane X element offsets
  int xoff[2][2];
  #pragma unroll
  for (int mi = 0; mi < 2; mi++)
    #pragma unroll
    for (int kt = 0; kt < 2; kt++)
      xoff[mi][kt] = (mts[mi] * 16 + c16) * 64 + kt * 32 + quad * 8;

  // ---- initial X load (batch b0) ----
  s8v xf[2][2];
  #pragma unroll
  for (int mi = 0; mi < 2; mi++)
    #pragma unroll
    for (int kt = 0; kt < 2; kt++) {
      if (isbf) xf[mi][kt] = *(const s8v*)((const unsigned short*)xg +
                                           (size_t)b0 * 8192 + xoff[mi][kt]);
      else      xf[mi][kt] = cvt8((const float*)xg + (size_t)b0 * 8192 + xoff[mi][kt]);
    }

  for (int it = 0; it < NIT; ++it) {
    const int b = b0 + NBLK * it;

    // ---- phase 1: Q^T (packed to bf16, 16 regs), K,V -> LDS ----
    unsigned qpk[2][4][2];   // [mi][ht][pair]
    #pragma unroll
    for (int ht = 0; ht < 4; ht++) {
      s8v wqf[2], wkf[2], wvf[2];
      const int woff0 = (ht * 16 + c16) * 64 + quad * 8;
      #pragma unroll
      for (int kt = 0; kt < 2; kt++) {
        const int off = woff0 + kt * 32;
        if (isbf) {
          wqf[kt] = *(const s8v*)((const unsigned short*)wqg + off);
          wkf[kt] = *(const s8v*)((const unsigned short*)wkg + off);
          wvf[kt] = *(const s8v*)((const unsigned short*)wvg + off);
        } else {
          wqf[kt] = cvt8((const float*)wqg + off);
          wkf[kt] = cvt8((const float*)wkg + off);
          wvf[kt] = cvt8((const float*)wvg + off);
        }
      }
      #pragma unroll
      for (int mi = 0; mi < 2; mi++) {
        const int m = mts[mi];
        f4 z = {0.f, 0.f, 0.f, 0.f};
        f4 qt = z, kk = z, vv = z;
        qt = MFMA16(wqf[0], xf[mi][0], qt);  qt = MFMA16(wqf[1], xf[mi][1], qt);
        // swapped operands: lane holds h = ht*16+quad*4+r for s = m*16+c16
        kk = MFMA16(wkf[0], xf[mi][0], kk);  kk = MFMA16(wkf[1], xf[mi][1], kk);
        vv = MFMA16(xf[mi][0], wvf[0], vv);  vv = MFMA16(xf[mi][1], wvf[1], vv);
        qpk[mi][ht][0] = cvtpk(qt[0] * 0.125f, qt[1] * 0.125f);
        qpk[mi][ht][1] = cvtpk(qt[2] * 0.125f, qt[3] * 0.125f);
        {  // K[s][h]: one 8B swizzled store
          union { unsigned u[2]; s4v v; } pk;
          pk.u[0] = cvtpk(kk[0], kk[1]); pk.u[1] = cvtpk(kk[2], kk[3]);
          *(s4v*)(Ksm + (m * 16 + c16) * 64 + ((ht * 16 + quad * 4) ^ swz)) = pk.v;
        }
        {  // V^T[h][s]: one 8B swizzled store
          union { unsigned u[2]; s4v v; } pv;
          pv.u[0] = cvtpk(vv[0], vv[1]); pv.u[1] = cvtpk(vv[2], vv[3]);
          *(s4v*)(Vt + (ht * 16 + c16) * 128 + ((m * 16 + quad * 4) ^ swz)) = pv.v;
        }
      }
    }

    __syncthreads();   // K,V ready

    // ---- prefetch next batch's X into the now-dead xf regs (bf16 path) ----
    // Issued after the barrier so the vmcnt(0) drain happens at the NEXT
    // barrier (post phase 2) -> ~900cy latency hidden under phase-2 compute.
    if (isbf && it + 1 < NIT) {
      const unsigned short* xb = (const unsigned short*)xg +
                                 (size_t)(b + NBLK) * 8192;
      #pragma unroll
      for (int mi = 0; mi < 2; mi++)
        #pragma unroll
        for (int kt = 0; kt < 2; kt++)
          xf[mi][kt] = *(const s8v*)(xb + xoff[mi][kt]);
    }

    // ---- phase 2 per M-tile: fused per-kt S^T -> exp -> P^T -> PV ----
    #pragma unroll
    for (int mi = 0; mi < 2; mi++) {
      const int m = mts[mi];
      const int q4 = quad * 4;
      const s8v qb0 = mk8(qpk[mi][0][0], qpk[mi][0][1], qpk[mi][1][0], qpk[mi][1][1]);
      const s8v qb1 = mk8(qpk[mi][2][0], qpk[mi][2][1], qpk[mi][3][0], qpk[mi][3][1]);

      f4 acc[4];
      #pragma unroll
      for (int ht = 0; ht < 4; ht++) { f4 z = {0.f,0.f,0.f,0.f}; acc[ht] = z; }
      float sum = 0.f;
      const int nchunk = (m >> 1) + 1;

      #pragma unroll
      for (int kt = 0; kt < 4; kt++) {
        if (kt >= nchunk) continue;           // wave-uniform causal K-range
        const int nt0 = 2 * kt, nt1 = 2 * kt + 1;
        const bool hb = nt1 <= m;             // wave-uniform

        f4 z = {0.f, 0.f, 0.f, 0.f};
        f4 s0 = z, s1 = z;
        {
          const short* kr = Ksm + (nt0 * 16 + c16) * 64;
          s0 = MFMA16(ld44(kr + ((q4     ) ^ swz), kr + ((q4 + 16) ^ swz)), qb0, s0);
          s0 = MFMA16(ld44(kr + ((q4 + 32) ^ swz), kr + ((q4 + 48) ^ swz)), qb1, s0);
        }
        if (hb) {
          const short* kr = Ksm + (nt1 * 16 + c16) * 64;
          s1 = MFMA16(ld44(kr + ((q4     ) ^ swz), kr + ((q4 + 16) ^ swz)), qb0, s1);
          s1 = MFMA16(ld44(kr + ((q4 + 32) ^ swz), kr + ((q4 + 48) ^ swz)), qb1, s1);
        }
        #pragma unroll
        for (int r = 0; r < 4; r++) {
          const bool k0 = (nt0 < m) || (q4 + r <= c16);
          float e0 = k0 ? __expf(s0[r]) : 0.0f;
          s0[r] = e0; sum += e0;
        }
        if (hb) {
          #pragma unroll
          for (int r = 0; r < 4; r++) {
            const bool k1 = (nt1 < m) || (q4 + r <= c16);
            float e1 = k1 ? __expf(s1[r]) : 0.0f;
            s1[r] = e1; sum += e1;
          }
        }
        // s1 stays all-zero when !hb -> upper half of pb packs to 0 (correct).
        const s8v pb = mk8(cvtpk(s0[0], s0[1]), cvtpk(s0[2], s0[3]),
                           cvtpk(s1[0], s1[1]), cvtpk(s1[2], s1[3]));
        #pragma unroll
        for (int ht = 0; ht < 4; ht++) {
          const short* vr = Vt + (ht * 16 + c16) * 128;
          const s8v va = ld44(vr + ((kt * 32 + q4     ) ^ swz),
                              vr + ((kt * 32 + q4 + 16) ^ swz));
          acc[ht] = MFMA16(va, pb, acc[ht]);
        }
      }

      sum += __shfl_xor(sum, 16);
      sum += __shfl_xor(sum, 32);
      const float inv = 1.0f / sum;           // normalize in epilogue

      // epilogue: O^T lane holds 4 consecutive h for query t=c16
      if (isbf) {
        unsigned short* op = (unsigned short*)outg + (size_t)b * 8192;
        #pragma unroll
        for (int ht = 0; ht < 4; ht++) {
          union { unsigned u[2]; s4v v; } o;
          o.u[0] = cvtpk(acc[ht][0] * inv, acc[ht][1] * inv);
          o.u[1] = cvtpk(acc[ht][2] * inv, acc[ht][3] * inv);
          *(s4v*)(op + (size_t)(m * 16 + c16) * 64 + ht * 16 + q4) = o.v;
        }
      } else {
        float* op = (float*)outg + (size_t)b * 8192;
        #pragma unroll
        for (int ht = 0; ht < 4; ht++) {
          float4 o = {acc[ht][0] * inv, acc[ht][1] * inv,
                      acc[ht][2] * inv, acc[ht][3] * inv};
          *(float4*)(op + (size_t)(m * 16 + c16) * 64 + ht * 16 + q4) = o;
        }
      }
    }

    if (it + 1 < NIT) {
      __syncthreads();   // protect LDS before next phase 1 overwrites it
      if (!isbf) {       // fp32 path: load next X here (no reg-safe prefetch)
        const float* xb = (const float*)xg + (size_t)(b + NBLK) * 8192;
        #pragma unroll
        for (int mi = 0; mi < 2; mi++)
          #pragma unroll
          for (int kt = 0; kt < 2; kt++)
            xf[mi][kt] = cvt8(xb + xoff[mi][kt]);
      }
    }
  }
}

extern "C" void kernel_launch(void* const* d_in, const int* in_sizes, int n_in,
                              void* d_out, int out_size, void* d_ws, size_t ws_size,
                              hipStream_t stream) {
  (void)d_ws; (void)ws_size; (void)in_sizes; (void)n_in; (void)out_size;
  attn_head<<<dim3(NBLK), dim3(256), 0, stream>>>(
      d_in[0], d_in[1], d_in[2], d_in[3], d_out);
}